// Round 1
// baseline (2205.309 us; speedup 1.0000x reference)
//
#include <hip/hip_runtime.h>
#include <math.h>

// Problem constants: B=4, C=256, H=W=64 -> HW=4096
#define HW 4096
#define NC 256
#define NB 4
#define EPSF 1e-5f

// Workspace layout (floats):
//  [0,1024)      meanC   (content per-(b,c) mean)
//  [1024,2048)   rstdC   (content 1/sqrt(var+eps), unbiased var)
//  [2048,3072)   meanS   (style)
//  [3072,4096)   rstdS
//  [4096, +TEN)  Q  [b][pix][ch]   (pixel-major)
//  next TEN      K  [b][pix][ch]
//  next TEN      V  [b][pix][ch]
// total = 4096 + 3*4194304 floats = ~50.4 MB
#define QOFF 4096
#define TEN (NB * HW * NC) // 4194304

// ---------------------------------------------------------------------------
// Kernel 1: per-(b,c) mean and rstd for content and style.
// One block per channel; 2048 blocks; coalesced float4 reads.
// ---------------------------------------------------------------------------
__global__ __launch_bounds__(256) void stats_kernel(
    const float* __restrict__ content, const float* __restrict__ style,
    float* __restrict__ ws) {
  int bc = blockIdx.x; // 0..2047; <1024 -> content, else style
  const float* src = (bc < 1024 ? content : style) + (size_t)(bc & 1023) * HW;
  int t = threadIdx.x;
  const float4* s4 = (const float4*)src;
  float sum = 0.f, ss = 0.f;
#pragma unroll
  for (int n = 0; n < 4; ++n) {
    float4 v = s4[t + n * 256];
    sum += v.x + v.y + v.z + v.w;
    ss += v.x * v.x + v.y * v.y + v.z * v.z + v.w * v.w;
  }
#pragma unroll
  for (int m = 1; m < 64; m <<= 1) {
    sum += __shfl_xor(sum, m, 64);
    ss += __shfl_xor(ss, m, 64);
  }
  __shared__ float redS[4], redQ[4];
  int w = t >> 6;
  if ((t & 63) == 0) { redS[w] = sum; redQ[w] = ss; }
  __syncthreads();
  if (t == 0) {
    float S = redS[0] + redS[1] + redS[2] + redS[3];
    float Q2 = redQ[0] + redQ[1] + redQ[2] + redQ[3];
    float mean = S * (1.0f / HW);
    float var = (Q2 - S * mean) * (1.0f / (HW - 1)); // unbiased (ddof=1)
    float rstd = rsqrtf(var + EPSF);
    float* meanArr = ws + (bc < 1024 ? 0 : 2048);
    float* rstdArr = meanArr + 1024;
    meanArr[bc & 1023] = mean;
    rstdArr[bc & 1023] = rstd;
  }
}

// ---------------------------------------------------------------------------
// Kernel 2: fused normalize + 1x1 conv (per-pixel GEMM).
//  tensor 0: Q = Wf @ mvn(content) + bf
//  tensor 1: K = Wg @ mvn(style)   + bg
//  tensor 2: V = Wh @ style        + bh
// Block tile: 128 pixels x 64 out-channels; k-chunks of 32 via LDS.
// Output stored pixel-major [b][pix][ch].
// ---------------------------------------------------------------------------
__global__ __launch_bounds__(256) void proj_kernel(
    const float* __restrict__ content, const float* __restrict__ style,
    const float* __restrict__ Wf, const float* __restrict__ bf,
    const float* __restrict__ Wg, const float* __restrict__ bg,
    const float* __restrict__ Wh, const float* __restrict__ bh,
    float* __restrict__ ws) {
  int pt = blockIdx.x; // 32 pixel tiles of 128
  int ot = blockIdx.y; // 4 out tiles of 64
  int z = blockIdx.z;  // tensor*4 + b
  int tensor = z >> 2, b = z & 3;

  const float* X; const float* Wm; const float* bias;
  const float* meanA = nullptr; const float* rstdA = nullptr;
  float* dst;
  if (tensor == 0)      { X = content; Wm = Wf; bias = bf; meanA = ws;        rstdA = ws + 1024; dst = ws + QOFF; }
  else if (tensor == 1) { X = style;   Wm = Wg; bias = bg; meanA = ws + 2048; rstdA = ws + 3072; dst = ws + QOFF + TEN; }
  else                  { X = style;   Wm = Wh; bias = bh;                                         dst = ws + QOFF + 2 * TEN; }

  __shared__ float Xs[32 * 132]; // [kk][pix], stride 132 (pad)
  __shared__ float Wt[32 * 68];  // [kk][o],   stride 68  (pad), transposed W

  int t = threadIdx.x;
  int p0 = pt * 128, o0 = ot * 64;
  int o_base = (t >> 4) * 4;   // 16 o-groups of 4
  int p_base = (t & 15) * 8;   // 16 p-groups of 8

  float bb[4];
  { float4 b4 = *(const float4*)&bias[o0 + o_base];
    bb[0] = b4.x; bb[1] = b4.y; bb[2] = b4.z; bb[3] = b4.w; }
  float acc[4][8];
#pragma unroll
  for (int oo = 0; oo < 4; ++oo)
#pragma unroll
    for (int pp = 0; pp < 8; ++pp) acc[oo][pp] = bb[oo];

  const float4* X4 = (const float4*)X;
  const float4* Wm4 = (const float4*)Wm;

  for (int kc = 0; kc < 8; ++kc) {
    int k0 = kc * 32;
    __syncthreads();
    // stage X chunk [32 k x 128 p], normalized for tensors 0/1
#pragma unroll
    for (int n = 0; n < 4; ++n) {
      int f = t + n * 256;
      int kk = f >> 5, p4 = f & 31;
      float4 v = X4[(size_t)(b * NC + k0 + kk) * (HW / 4) + (p0 / 4) + p4];
      if (tensor < 2) {
        float mC = meanA[b * NC + k0 + kk], rC = rstdA[b * NC + k0 + kk];
        v.x = (v.x - mC) * rC; v.y = (v.y - mC) * rC;
        v.z = (v.z - mC) * rC; v.w = (v.w - mC) * rC;
      }
      *(float4*)&Xs[kk * 132 + p4 * 4] = v;
    }
    // stage W chunk transposed: Wt[kk][o] = W[o0+o][k0+kk]
#pragma unroll
    for (int n = 0; n < 2; ++n) {
      int f = t + n * 256;
      int o = f >> 3, k4 = f & 7;
      float4 v = Wm4[(size_t)(o0 + o) * (NC / 4) + kc * 8 + k4];
      Wt[(k4 * 4 + 0) * 68 + o] = v.x;
      Wt[(k4 * 4 + 1) * 68 + o] = v.y;
      Wt[(k4 * 4 + 2) * 68 + o] = v.z;
      Wt[(k4 * 4 + 3) * 68 + o] = v.w;
    }
    __syncthreads();
#pragma unroll
    for (int kk = 0; kk < 32; ++kk) {
      float4 w4 = *(float4*)&Wt[kk * 68 + o_base];
      float4 xa = *(float4*)&Xs[kk * 132 + p_base];
      float4 xb = *(float4*)&Xs[kk * 132 + p_base + 4];
      float wv[4] = {w4.x, w4.y, w4.z, w4.w};
      float xv[8] = {xa.x, xa.y, xa.z, xa.w, xb.x, xb.y, xb.z, xb.w};
#pragma unroll
      for (int oo = 0; oo < 4; ++oo)
#pragma unroll
        for (int pp = 0; pp < 8; ++pp)
          acc[oo][pp] = fmaf(wv[oo], xv[pp], acc[oo][pp]);
    }
  }
  float4* dst4 = (float4*)dst;
#pragma unroll
  for (int pp = 0; pp < 8; ++pp) {
    float4 o4 = {acc[0][pp], acc[1][pp], acc[2][pp], acc[3][pp]};
    dst4[((size_t)b * HW + p0 + p_base + pp) * (NC / 4) + (o0 + o_base) / 4] = o4;
  }
}

// ---------------------------------------------------------------------------
// Kernel 3: flash attention, fp32 VALU.
// Block = 32 queries (one batch), 256 threads: lane (iloc = t>>3, g = t&7).
// Q row fragment in registers (lane g holds cols g*32..g*32+31).
// K/V 32-key tiles staged in LDS with float4-chunk XOR swizzle (c4 ^ (c4>>3))
// -> conflict-free for load, logit-read, and PV-read patterns.
// Online softmax; accumulate S@V and S@V^2; fused epilogue writes
// out / mean / std in [b][c][pix] layout.
// ---------------------------------------------------------------------------
__global__ __launch_bounds__(256, 2) void attn_kernel(
    const float* __restrict__ ws, const float* __restrict__ content,
    float* __restrict__ dout) {
  const float* Qb = ws + QOFF;
  const float* Kb = Qb + TEN;
  const float* Vb = Kb + TEN;
  const float* meanC = ws;
  const float* rstdC = ws + 1024;

  int qt = blockIdx.x, b = blockIdx.y;
  int t = threadIdx.x;
  int iloc = t >> 3; // 0..31 query row in tile
  int g = t & 7;     // k/column split group
  int qi = qt * 32 + iloc;

  __shared__ float4 Abuf[32 * 64]; // K tile, swizzled chunks
  __shared__ float4 Bbuf[32 * 64]; // V tile, swizzled chunks

  float4 qv[8];
  { const float4* Q4 = (const float4*)(Qb + ((size_t)b * HW + qi) * NC);
#pragma unroll
    for (int u = 0; u < 8; ++u) qv[u] = Q4[g * 8 + u]; }

  float accm[32], accs[32];
#pragma unroll
  for (int c2 = 0; c2 < 32; ++c2) { accm[c2] = 0.f; accs[c2] = 0.f; }
  float mrun = -INFINITY, lrun = 0.f;

  const float4* K4 = (const float4*)(Kb + (size_t)b * HW * NC);
  const float4* V4 = (const float4*)(Vb + (size_t)b * HW * NC);

  for (int kt = 0; kt < 128; ++kt) {
    __syncthreads(); // previous tile's LDS reads done
#pragma unroll
    for (int n = 0; n < 8; ++n) {
      int idx = t + n * 256;
      int row = idx >> 6, c4 = idx & 63;
      int c4s = c4 ^ (c4 >> 3); // chunk swizzle
      size_t gchunk = (size_t)(kt * 32 + row) * 64 + c4;
      Abuf[row * 64 + c4s] = K4[gchunk];
      Bbuf[row * 64 + c4s] = V4[gchunk];
    }
    __syncthreads();

    // --- logits: partial dot over own k-range, butterfly over 8 lanes ---
    float lg[32];
#pragma unroll
    for (int j = 0; j < 32; ++j) {
      float s0 = 0.f;
#pragma unroll
      for (int u = 0; u < 8; ++u) {
        float4 kv = Abuf[j * 64 + g * 8 + (u ^ g)];
        s0 = fmaf(qv[u].x, kv.x, s0);
        s0 = fmaf(qv[u].y, kv.y, s0);
        s0 = fmaf(qv[u].z, kv.z, s0);
        s0 = fmaf(qv[u].w, kv.w, s0);
      }
      s0 += __shfl_xor(s0, 1, 64);
      s0 += __shfl_xor(s0, 2, 64);
      s0 += __shfl_xor(s0, 4, 64);
      lg[j] = s0; // every lane of the 8-group now has the full dot
    }

    // --- online softmax update (identical in all 8 lanes of a row) ---
    float tmax = lg[0];
#pragma unroll
    for (int j = 1; j < 32; ++j) tmax = fmaxf(tmax, lg[j]);
    float mnew = fmaxf(mrun, tmax);
    float alpha = __expf(mrun - mnew); // first tile: exp(-inf)=0
    float psum = 0.f;
#pragma unroll
    for (int j = 0; j < 32; ++j) { lg[j] = __expf(lg[j] - mnew); psum += lg[j]; }
    lrun = lrun * alpha + psum;
    mrun = mnew;
#pragma unroll
    for (int c2 = 0; c2 < 32; ++c2) { accm[c2] *= alpha; accs[c2] *= alpha; }

    // --- PV: accumulate p*V and p*V^2 over this key tile ---
#pragma unroll
    for (int j = 0; j < 32; ++j) {
      float pj = lg[j];
#pragma unroll
      for (int s = 0; s < 8; ++s) {
        float4 v4 = Bbuf[j * 64 + g * 8 + (s ^ g)];
        float pv;
        pv = pj * v4.x; accm[4 * s + 0] += pv; accs[4 * s + 0] = fmaf(pv, v4.x, accs[4 * s + 0]);
        pv = pj * v4.y; accm[4 * s + 1] += pv; accs[4 * s + 1] = fmaf(pv, v4.y, accs[4 * s + 1]);
        pv = pj * v4.z; accm[4 * s + 2] += pv; accs[4 * s + 2] = fmaf(pv, v4.z, accs[4 * s + 2]);
        pv = pj * v4.w; accm[4 * s + 3] += pv; accs[4 * s + 3] = fmaf(pv, v4.w, accs[4 * s + 3]);
      }
    }
  }

  // --- epilogue: mean, std, out (channel-major output layout) ---
  float invl = 1.0f / lrun;
  size_t obase = (size_t)b * NC * HW;
#pragma unroll
  for (int c2 = 0; c2 < 32; ++c2) {
    int ch = g * 32 + c2;
    float mu = accm[c2] * invl;
    float sec = accs[c2] * invl;
    float var = sec - mu * mu;
    float sd = sqrtf(fmaxf(var, 0.f)); // sqrt(relu(...))
    size_t idx = obase + (size_t)ch * HW + qi;
    float xc = content[idx];
    float nc = (xc - meanC[b * NC + ch]) * rstdC[b * NC + ch];
    dout[idx] = sd * nc + mu;      // out
    dout[TEN + idx] = mu;          // mean
    dout[2 * TEN + idx] = sd;      // std
  }
}

// ---------------------------------------------------------------------------
extern "C" void kernel_launch(void* const* d_in, const int* in_sizes, int n_in,
                              void* d_out, int out_size, void* d_ws, size_t ws_size,
                              hipStream_t stream) {
  const float* content = (const float*)d_in[0];
  const float* style   = (const float*)d_in[1];
  const float* Wf = (const float*)d_in[2];
  const float* bf = (const float*)d_in[3];
  const float* Wg = (const float*)d_in[4];
  const float* bg = (const float*)d_in[5];
  const float* Wh = (const float*)d_in[6];
  const float* bh = (const float*)d_in[7];
  float* ws = (float*)d_ws;
  float* out = (float*)d_out;

  hipLaunchKernelGGL(stats_kernel, dim3(2048), dim3(256), 0, stream,
                     content, style, ws);
  hipLaunchKernelGGL(proj_kernel, dim3(32, 4, 12), dim3(256), 0, stream,
                     content, style, Wf, bf, Wg, bg, Wh, bh, ws);
  hipLaunchKernelGGL(attn_kernel, dim3(128, 4), dim3(256), 0, stream,
                     ws, content, out);
}

// Round 3
// 1354.049 us; speedup vs baseline: 1.6287x; 1.6287x over previous
//
#include <hip/hip_runtime.h>
#include <math.h>

// Problem constants: B=4, C=256, H=W=64 -> HW=4096
#define HW 4096
#define NC 256
#define NB 4
#define EPSF 1e-5f
#define TEN (NB * HW * NC)  // elements per output tensor = 4194304

typedef _Float16 half8 __attribute__((ext_vector_type(8)));
typedef _Float16 half4v __attribute__((ext_vector_type(4)));
typedef float f32x4 __attribute__((ext_vector_type(4)));

// ws layout (bytes):
//  [0, 16K)            stats f32: meanC[1024], rstdC[1024], meanS[1024], rstdS[1024]
//  QF : f16 [b][pix][256]  (pixel-major)   -- Q = Wf*mvn(content)+bf
//  KF : f16 [b][pix][256]  (pixel-major)   -- K = Wg*mvn(style)+bg
//  VF : f16 [b][ch][4096]  (channel-major) -- V = Wh*style+bh
//  V2H: f16 [b][ch][4096]  -- hi part of (f16 V)^2
//  V2L: f16 [b][ch][4096]  -- lo part, v2 = V2H + V2L exactly (22-bit)
// total = 16 KB + 5 * 8 MB = ~41.9 MB  (< round-0-proven 50.4 MB)
#define STATS_BYTES (4096 * 4)
#define QF_OFF  (STATS_BYTES)
#define KF_OFF  (QF_OFF + TEN * 2)
#define VF_OFF  (KF_OFF + TEN * 2)
#define V2H_OFF (VF_OFF + TEN * 2)
#define V2L_OFF (V2H_OFF + TEN * 2)

// ---------------------------------------------------------------------------
// Kernel 1: per-(b,c) mean and rstd for content and style. (unchanged)
// ---------------------------------------------------------------------------
__global__ __launch_bounds__(256) void stats_kernel(
    const float* __restrict__ content, const float* __restrict__ style,
    float* __restrict__ ws) {
  int bc = blockIdx.x;
  const float* src = (bc < 1024 ? content : style) + (size_t)(bc & 1023) * HW;
  int t = threadIdx.x;
  const float4* s4 = (const float4*)src;
  float sum = 0.f, ss = 0.f;
#pragma unroll
  for (int n = 0; n < 4; ++n) {
    float4 v = s4[t + n * 256];
    sum += v.x + v.y + v.z + v.w;
    ss += v.x * v.x + v.y * v.y + v.z * v.z + v.w * v.w;
  }
#pragma unroll
  for (int m = 1; m < 64; m <<= 1) {
    sum += __shfl_xor(sum, m, 64);
    ss += __shfl_xor(ss, m, 64);
  }
  __shared__ float redS[4], redQ[4];
  int w = t >> 6;
  if ((t & 63) == 0) { redS[w] = sum; redQ[w] = ss; }
  __syncthreads();
  if (t == 0) {
    float S = redS[0] + redS[1] + redS[2] + redS[3];
    float Q2 = redQ[0] + redQ[1] + redQ[2] + redQ[3];
    float mean = S * (1.0f / HW);
    float var = (Q2 - S * mean) * (1.0f / (HW - 1));
    float rstd = rsqrtf(var + EPSF);
    float* meanArr = ws + (bc < 1024 ? 0 : 2048);
    float* rstdArr = meanArr + 1024;
    meanArr[bc & 1023] = mean;
    rstdArr[bc & 1023] = rstd;
  }
}

// ---------------------------------------------------------------------------
// Kernel 2: fused normalize + 1x1 conv; f16 outputs for the MFMA attention.
//  tensor 0: Q -> QF pixel-major f16
//  tensor 1: K -> KF pixel-major f16
//  tensor 2: V -> VF channel-major f16, plus V2H/V2L = exact hi/lo of V^2
// ---------------------------------------------------------------------------
__global__ __launch_bounds__(256) void proj_kernel(
    const float* __restrict__ content, const float* __restrict__ style,
    const float* __restrict__ Wf, const float* __restrict__ bf,
    const float* __restrict__ Wg, const float* __restrict__ bg,
    const float* __restrict__ Wh, const float* __restrict__ bh,
    char* __restrict__ wsb) {
  float* ws = (float*)wsb;
  int pt = blockIdx.x;
  int ot = blockIdx.y;
  int z = blockIdx.z;
  int tensor = z >> 2, b = z & 3;

  const float* X; const float* Wm; const float* bias;
  const float* meanA = nullptr; const float* rstdA = nullptr;
  if (tensor == 0)      { X = content; Wm = Wf; bias = bf; meanA = ws;        rstdA = ws + 1024; }
  else if (tensor == 1) { X = style;   Wm = Wg; bias = bg; meanA = ws + 2048; rstdA = ws + 3072; }
  else                  { X = style;   Wm = Wh; bias = bh; }

  __shared__ float Xs[32 * 132];
  __shared__ float Wt[32 * 68];

  int t = threadIdx.x;
  int p0 = pt * 128, o0 = ot * 64;
  int o_base = (t >> 4) * 4;
  int p_base = (t & 15) * 8;

  float bb[4];
  { float4 b4 = *(const float4*)&bias[o0 + o_base];
    bb[0] = b4.x; bb[1] = b4.y; bb[2] = b4.z; bb[3] = b4.w; }
  float acc[4][8];
#pragma unroll
  for (int oo = 0; oo < 4; ++oo)
#pragma unroll
    for (int pp = 0; pp < 8; ++pp) acc[oo][pp] = bb[oo];

  const float4* X4 = (const float4*)X;
  const float4* Wm4 = (const float4*)Wm;

  for (int kc = 0; kc < 8; ++kc) {
    int k0 = kc * 32;
    __syncthreads();
#pragma unroll
    for (int n = 0; n < 4; ++n) {
      int f = t + n * 256;
      int kk = f >> 5, p4 = f & 31;
      float4 v = X4[(size_t)(b * NC + k0 + kk) * (HW / 4) + (p0 / 4) + p4];
      if (tensor < 2) {
        float mC = meanA[b * NC + k0 + kk], rC = rstdA[b * NC + k0 + kk];
        v.x = (v.x - mC) * rC; v.y = (v.y - mC) * rC;
        v.z = (v.z - mC) * rC; v.w = (v.w - mC) * rC;
      }
      *(float4*)&Xs[kk * 132 + p4 * 4] = v;
    }
#pragma unroll
    for (int n = 0; n < 2; ++n) {
      int f = t + n * 256;
      int o = f >> 3, k4 = f & 7;
      float4 v = Wm4[(size_t)(o0 + o) * (NC / 4) + kc * 8 + k4];
      Wt[(k4 * 4 + 0) * 68 + o] = v.x;
      Wt[(k4 * 4 + 1) * 68 + o] = v.y;
      Wt[(k4 * 4 + 2) * 68 + o] = v.z;
      Wt[(k4 * 4 + 3) * 68 + o] = v.w;
    }
    __syncthreads();
#pragma unroll
    for (int kk = 0; kk < 32; ++kk) {
      float4 w4 = *(float4*)&Wt[kk * 68 + o_base];
      float4 xa = *(float4*)&Xs[kk * 132 + p_base];
      float4 xb = *(float4*)&Xs[kk * 132 + p_base + 4];
      float wv[4] = {w4.x, w4.y, w4.z, w4.w};
      float xv[8] = {xa.x, xa.y, xa.z, xa.w, xb.x, xb.y, xb.z, xb.w};
#pragma unroll
      for (int oo = 0; oo < 4; ++oo)
#pragma unroll
        for (int pp = 0; pp < 8; ++pp)
          acc[oo][pp] = fmaf(wv[oo], xv[pp], acc[oo][pp]);
    }
  }

  if (tensor < 2) {
    // pixel-major f16: [b][pix][256]
    _Float16* dst = (_Float16*)(wsb + (tensor == 0 ? QF_OFF : KF_OFF));
#pragma unroll
    for (int pp = 0; pp < 8; ++pp) {
      half4v h;
      h[0] = (_Float16)acc[0][pp]; h[1] = (_Float16)acc[1][pp];
      h[2] = (_Float16)acc[2][pp]; h[3] = (_Float16)acc[3][pp];
      *(half4v*)&dst[((size_t)(b * HW) + p0 + p_base + pp) * 256 + o0 + o_base] = h;
    }
  } else {
    // channel-major f16: [b][ch][4096], plus exact hi/lo of v^2
    _Float16* dV  = (_Float16*)(wsb + VF_OFF);
    _Float16* dH  = (_Float16*)(wsb + V2H_OFF);
    _Float16* dL  = (_Float16*)(wsb + V2L_OFF);
#pragma unroll
    for (int oo = 0; oo < 4; ++oo) {
      int ch = o0 + o_base + oo;
      half8 hv, hh, hl;
#pragma unroll
      for (int pp = 0; pp < 8; ++pp) {
        _Float16 vh = (_Float16)acc[oo][pp];
        float vf = (float)vh;
        float v2 = vf * vf;
        _Float16 v2h = (_Float16)v2;
        _Float16 v2l = (_Float16)(v2 - (float)v2h);
        hv[pp] = vh; hh[pp] = v2h; hl[pp] = v2l;
      }
      size_t base = ((size_t)(b * NC) + ch) * HW + p0 + p_base;
      *(half8*)&dV[base] = hv;
      *(half8*)&dH[base] = hh;
      *(half8*)&dL[base] = hl;
    }
  }
}

// ---------------------------------------------------------------------------
// Kernel 3: flash attention with mfma_f32_16x16x32_f16.
// Block = 256 thr = 4 waves; q-tile 64; waves = (qh, chh): qh = query half
// (32 q each, 2 mtiles of 16), chh = channel half for PV (128 ch, 8 ntiles).
// Key tile = 32.  LDS (64 KB): K[16K] | V[16K] | V2h[16K] | V2l[16K],
// P (4 KB) aliases the K buffer after QK reads complete.
// All LDS tiles are 16-B-granule XOR-swizzled for conflict-free frag reads.
// Online softmax; denominator = fp32 sum of the f16-rounded P (weights sum
// to exactly 1 -> variance stays a true weighted variance).
// ---------------------------------------------------------------------------
__global__ __launch_bounds__(256, 1) void attn_kernel(
    const char* __restrict__ wsb, const float* __restrict__ content,
    float* __restrict__ dout) {
  const _Float16* Qf  = (const _Float16*)(wsb + QF_OFF);
  const _Float16* Kf  = (const _Float16*)(wsb + KF_OFF);
  const _Float16* Vf  = (const _Float16*)(wsb + VF_OFF);
  const _Float16* V2h = (const _Float16*)(wsb + V2H_OFF);
  const _Float16* V2l = (const _Float16*)(wsb + V2L_OFF);
  const float* meanC = (const float*)wsb;
  const float* rstdC = meanC + 1024;

  int qt = blockIdx.x, b = blockIdx.y;
  int t = threadIdx.x;
  int lane = t & 63;
  int w = t >> 6;
  int qh = w >> 1;   // 0,1: which 32 queries
  int chh = w & 1;   // 0,1: which 128 channels for PV
  int q0 = qt * 64;
  int ml = lane & 15;   // m/n position inside a 16-wide mfma tile
  int kg4 = lane >> 4;  // 0..3 quad

  __shared__ int4 smem[4096];  // 64 KB
  _Float16* Kt   = (_Float16*)smem;                    // 16 KB (granule: c*32 + (key^c))
  _Float16* Vt   = (_Float16*)((char*)smem + 16384);   // granule: kg*256 + (ch^kg)
  _Float16* V2ht = (_Float16*)((char*)smem + 32768);
  _Float16* V2lt = (_Float16*)((char*)smem + 49152);
  _Float16* Pt   = (_Float16*)smem;                    // 4 KB, aliases Kt

  // ---- preload Q A-frags (per-wave 32 queries x 256 ch, f16) ----
  half8 Aq[2][8];
#pragma unroll
  for (int mt = 0; mt < 2; ++mt)
#pragma unroll
    for (int ks = 0; ks < 8; ++ks) {
      size_t off = ((size_t)(b * HW) + q0 + qh * 32 + mt * 16 + ml) * 256 +
                   ks * 32 + kg4 * 8;
      Aq[mt][ks] = *(const half8*)(Qf + off);
    }

  f32x4 accm[2][8], accs[2][8];  // [mtile][ntile]: mean and second-moment
#pragma unroll
  for (int mt = 0; mt < 2; ++mt)
#pragma unroll
    for (int nt = 0; nt < 8; ++nt) {
      accm[mt][nt] = (f32x4){0.f, 0.f, 0.f, 0.f};
      accs[mt][nt] = (f32x4){0.f, 0.f, 0.f, 0.f};
    }
  float mrun[2][4], lrun[2][4];
#pragma unroll
  for (int mt = 0; mt < 2; ++mt)
#pragma unroll
    for (int r = 0; r < 4; ++r) { mrun[mt][r] = -INFINITY; lrun[mt][r] = 0.f; }

  for (int kt = 0; kt < 128; ++kt) {
    __syncthreads();  // prev tile's PV (V*, P) reads done -> safe to restage

    // ---- stage K tile: 32 keys x 256 ch, pixel-major rows, swizzled ----
    {
      int key = t >> 3;           // 0..31
      int c0 = (t & 7) * 4;       // 4 granules of 8 ch
      const int4* gk = (const int4*)(Kf + ((size_t)(b * HW) + kt * 32 + key) * 256);
      int4* kt16 = (int4*)Kt;
#pragma unroll
      for (int i = 0; i < 4; ++i) {
        int c = c0 + i;
        kt16[c * 32 + (key ^ c)] = gk[c];
      }
    }
    // ---- stage V / V2h / V2l tiles: 256 ch x 32 keys, channel-major ----
    {
      int kg = t & 3;
      int chb = t >> 2;  // 0..63
      int4* v16 = (int4*)Vt; int4* h16 = (int4*)V2ht; int4* l16 = (int4*)V2lt;
#pragma unroll
      for (int i = 0; i < 4; ++i) {
        int ch = chb + 64 * i;
        size_t g = ((size_t)(b * NC) + ch) * HW + kt * 32 + kg * 8;
        int dsti = kg * 256 + (ch ^ kg);
        v16[dsti] = *(const int4*)(Vf + g);
        h16[dsti] = *(const int4*)(V2h + g);
        l16[dsti] = *(const int4*)(V2l + g);
      }
    }
    __syncthreads();  // tiles visible

    // ---- QK^T: S[2 mt][2 nt], f32 ----
    f32x4 S[2][2];
#pragma unroll
    for (int mt = 0; mt < 2; ++mt)
#pragma unroll
      for (int nt = 0; nt < 2; ++nt) S[mt][nt] = (f32x4){0.f, 0.f, 0.f, 0.f};
#pragma unroll
    for (int ks = 0; ks < 8; ++ks) {
#pragma unroll
      for (int nt = 0; nt < 2; ++nt) {
        int key = nt * 16 + ml;
        int c = ks * 4 + kg4;
        half8 Bk = *(const half8*)(Kt + (c * 32 + (key ^ c)) * 8);
        S[0][nt] = __builtin_amdgcn_mfma_f32_16x16x32_f16(Aq[0][ks], Bk, S[0][nt], 0, 0, 0);
        S[1][nt] = __builtin_amdgcn_mfma_f32_16x16x32_f16(Aq[1][ks], Bk, S[1][nt], 0, 0, 0);
      }
    }

    // ---- online softmax (rows r of each mtile; cols across lane&15) ----
    bool noup = true;
    float alpha[2][4];
#pragma unroll
    for (int mt = 0; mt < 2; ++mt) {
#pragma unroll
      for (int r = 0; r < 4; ++r) {
        float tm = fmaxf(S[mt][0][r], S[mt][1][r]);
        tm = fmaxf(tm, __shfl_xor(tm, 1, 64));
        tm = fmaxf(tm, __shfl_xor(tm, 2, 64));
        tm = fmaxf(tm, __shfl_xor(tm, 4, 64));
        tm = fmaxf(tm, __shfl_xor(tm, 8, 64));
        float mold = mrun[mt][r];
        float mn = fmaxf(mold, tm);
        float a = __expf(mold - mn);
        alpha[mt][r] = a;
        noup = noup && (mn == mold);
        mrun[mt][r] = mn;
        float rs = 0.f;
#pragma unroll
        for (int nt = 0; nt < 2; ++nt) {
          float p = __expf(S[mt][nt][r] - mn);
          _Float16 ph = (_Float16)p;
          S[mt][nt][r] = (float)ph;  // keep the ROUNDED value
          rs += (float)ph;
        }
        rs += __shfl_xor(rs, 1, 64);
        rs += __shfl_xor(rs, 2, 64);
        rs += __shfl_xor(rs, 4, 64);
        rs += __shfl_xor(rs, 8, 64);
        lrun[mt][r] = lrun[mt][r] * a + rs;
      }
    }
    if (!__all((int)noup)) {
#pragma unroll
      for (int mt = 0; mt < 2; ++mt)
#pragma unroll
        for (int nt = 0; nt < 8; ++nt)
#pragma unroll
          for (int r = 0; r < 4; ++r) {
            accm[mt][nt][r] *= alpha[mt][r];
            accs[mt][nt][r] *= alpha[mt][r];
          }
    }

    __syncthreads();  // all QK reads of Kt done before P overwrites it

    // ---- P (D-layout) -> LDS in A-layout granules [kg][qloc] ----
    if (chh == 0) {
#pragma unroll
      for (int mt = 0; mt < 2; ++mt)
#pragma unroll
        for (int nt = 0; nt < 2; ++nt)
#pragma unroll
          for (int r = 0; r < 4; ++r) {
            int qloc = mt * 16 + kg4 * 4 + r;
            int key = nt * 16 + ml;
            Pt[qh * 1024 + ((key >> 3) * 32 + qloc) * 8 + (key & 7)] =
                (_Float16)S[mt][nt][r];
          }
    }
    __syncthreads();  // P visible

    // ---- PV: mean += P*V ; sec += P*V2h + P*V2l ----
    half8 Ap[2];
#pragma unroll
    for (int mt = 0; mt < 2; ++mt) {
      int qloc = mt * 16 + ml;
      Ap[mt] = *(const half8*)(Pt + qh * 1024 + (kg4 * 32 + qloc) * 8);
    }
#pragma unroll
    for (int nt = 0; nt < 8; ++nt) {
      int ch = chh * 128 + nt * 16 + ml;
      int gi = (kg4 * 256 + (ch ^ kg4)) * 8;
      half8 Bv = *(const half8*)(Vt + gi);
      half8 Bh = *(const half8*)(V2ht + gi);
      half8 Bl = *(const half8*)(V2lt + gi);
#pragma unroll
      for (int mt = 0; mt < 2; ++mt) {
        accm[mt][nt] = __builtin_amdgcn_mfma_f32_16x16x32_f16(Ap[mt], Bv, accm[mt][nt], 0, 0, 0);
        accs[mt][nt] = __builtin_amdgcn_mfma_f32_16x16x32_f16(Ap[mt], Bh, accs[mt][nt], 0, 0, 0);
        accs[mt][nt] = __builtin_amdgcn_mfma_f32_16x16x32_f16(Ap[mt], Bl, accs[mt][nt], 0, 0, 0);
      }
    }
  }

  // ---- finalize: accm := mu, accs := sd ----
  float inv[2][4];
#pragma unroll
  for (int mt = 0; mt < 2; ++mt)
#pragma unroll
    for (int r = 0; r < 4; ++r) inv[mt][r] = 1.0f / lrun[mt][r];
#pragma unroll
  for (int mt = 0; mt < 2; ++mt)
#pragma unroll
    for (int nt = 0; nt < 8; ++nt)
#pragma unroll
      for (int r = 0; r < 4; ++r) {
        float mu = accm[mt][nt][r] * inv[mt][r];
        float s2 = accs[mt][nt][r] * inv[mt][r];
        float var = s2 - mu * mu;
        accm[mt][nt][r] = mu;
        accs[mt][nt][r] = sqrtf(fmaxf(var, 0.f));
      }

  // ---- coalesced epilogue via LDS transpose: 4 phases of 64 channels ----
  float* MUL = (float*)smem;                    // [64][68]
  float* SDL = (float*)((char*)smem + 17408);   // [64][68]
#pragma unroll 1
  for (int ph = 0; ph < 4; ++ph) {
    __syncthreads();
    if (chh == (ph >> 1)) {
      int ntb = (ph & 1) * 4;
#pragma unroll
      for (int mt = 0; mt < 2; ++mt)
#pragma unroll
        for (int nn = 0; nn < 4; ++nn)
#pragma unroll
          for (int r = 0; r < 4; ++r) {
            int row64 = nn * 16 + ml;
            int ql = qh * 32 + mt * 16 + kg4 * 4 + r;
            MUL[row64 * 68 + ql] = accm[mt][ntb + nn][r];
            SDL[row64 * 68 + ql] = accs[mt][ntb + nn][r];
          }
    }
    __syncthreads();
    int qq = (t & 15) * 4;
#pragma unroll
    for (int i = 0; i < 4; ++i) {
      int chl = (t >> 4) + 16 * i;
      int ch = ph * 64 + chl;
      float4 mu4 = *(float4*)&MUL[chl * 68 + qq];
      float4 sd4 = *(float4*)&SDL[chl * 68 + qq];
      size_t base = ((size_t)(b * NC) + ch) * HW + q0 + qq;
      float4 c4 = *(const float4*)&content[base];
      float mC = meanC[b * NC + ch];
      float rC = rstdC[b * NC + ch];
      float4 o4;
      o4.x = sd4.x * ((c4.x - mC) * rC) + mu4.x;
      o4.y = sd4.y * ((c4.y - mC) * rC) + mu4.y;
      o4.z = sd4.z * ((c4.z - mC) * rC) + mu4.z;
      o4.w = sd4.w * ((c4.w - mC) * rC) + mu4.w;
      *(float4*)&dout[base] = o4;
      *(float4*)&dout[TEN + base] = mu4;
      *(float4*)&dout[2 * TEN + base] = sd4;
    }
  }
}

// ---------------------------------------------------------------------------
extern "C" void kernel_launch(void* const* d_in, const int* in_sizes, int n_in,
                              void* d_out, int out_size, void* d_ws, size_t ws_size,
                              hipStream_t stream) {
  const float* content = (const float*)d_in[0];
  const float* style   = (const float*)d_in[1];
  const float* Wf = (const float*)d_in[2];
  const float* bf = (const float*)d_in[3];
  const float* Wg = (const float*)d_in[4];
  const float* bg = (const float*)d_in[5];
  const float* Wh = (const float*)d_in[6];
  const float* bh = (const float*)d_in[7];
  char* wsb = (char*)d_ws;
  float* out = (float*)d_out;

  hipLaunchKernelGGL(stats_kernel, dim3(2048), dim3(256), 0, stream,
                     content, style, (float*)wsb);
  hipLaunchKernelGGL(proj_kernel, dim3(32, 4, 12), dim3(256), 0, stream,
                     content, style, Wf, bf, Wg, bg, Wh, bh, wsb);
  hipLaunchKernelGGL(attn_kernel, dim3(64, 4), dim3(256), 0, stream,
                     wsb, content, out);
}

// Round 4
// 839.041 us; speedup vs baseline: 2.6284x; 1.6138x over previous
//
#include <hip/hip_runtime.h>
#include <math.h>

// Problem constants: B=4, C=256, H=W=64 -> HW=4096
#define HW 4096
#define NC 256
#define NB 4
#define EPSF 1e-5f
#define TEN (NB * HW * NC)  // elements per output tensor = 4194304

typedef _Float16 half8 __attribute__((ext_vector_type(8)));
typedef _Float16 half4v __attribute__((ext_vector_type(4)));
typedef float f32x4 __attribute__((ext_vector_type(4)));

// ws layout (bytes):
//  [0, 16K)   stats f32: meanC[1024], rstdC[1024], meanS[1024], rstdS[1024]
//  QF : f16 [b][pix][256]  (pixel-major)
//  KF : f16 [b][pix][256]  (pixel-major)
//  VF : f16 [b][ch][4096]  (channel-major)
//  V2H: f16 [b][ch][4096]  hi part of (f16 V)^2
//  V2L: f16 [b][ch][4096]  lo part (exact hi+lo split)
#define STATS_BYTES (4096 * 4)
#define QF_OFF  (STATS_BYTES)
#define KF_OFF  (QF_OFF + TEN * 2)
#define VF_OFF  (KF_OFF + TEN * 2)
#define V2H_OFF (VF_OFF + TEN * 2)
#define V2L_OFF (V2H_OFF + TEN * 2)

// ---------------------------------------------------------------------------
// Kernel 1: per-(b,c) mean and rstd for content and style. (unchanged)
// ---------------------------------------------------------------------------
__global__ __launch_bounds__(256) void stats_kernel(
    const float* __restrict__ content, const float* __restrict__ style,
    float* __restrict__ ws) {
  int bc = blockIdx.x;
  const float* src = (bc < 1024 ? content : style) + (size_t)(bc & 1023) * HW;
  int t = threadIdx.x;
  const float4* s4 = (const float4*)src;
  float sum = 0.f, ss = 0.f;
#pragma unroll
  for (int n = 0; n < 4; ++n) {
    float4 v = s4[t + n * 256];
    sum += v.x + v.y + v.z + v.w;
    ss += v.x * v.x + v.y * v.y + v.z * v.z + v.w * v.w;
  }
#pragma unroll
  for (int m = 1; m < 64; m <<= 1) {
    sum += __shfl_xor(sum, m, 64);
    ss += __shfl_xor(ss, m, 64);
  }
  __shared__ float redS[4], redQ[4];
  int w = t >> 6;
  if ((t & 63) == 0) { redS[w] = sum; redQ[w] = ss; }
  __syncthreads();
  if (t == 0) {
    float S = redS[0] + redS[1] + redS[2] + redS[3];
    float Q2 = redQ[0] + redQ[1] + redQ[2] + redQ[3];
    float mean = S * (1.0f / HW);
    float var = (Q2 - S * mean) * (1.0f / (HW - 1));
    float rstd = rsqrtf(var + EPSF);
    float* meanArr = ws + (bc < 1024 ? 0 : 2048);
    float* rstdArr = meanArr + 1024;
    meanArr[bc & 1023] = mean;
    rstdArr[bc & 1023] = rstd;
  }
}

// ---------------------------------------------------------------------------
// Kernel 2: fused normalize + 1x1 conv; f16 outputs. (unchanged from r3)
// ---------------------------------------------------------------------------
__global__ __launch_bounds__(256) void proj_kernel(
    const float* __restrict__ content, const float* __restrict__ style,
    const float* __restrict__ Wf, const float* __restrict__ bf,
    const float* __restrict__ Wg, const float* __restrict__ bg,
    const float* __restrict__ Wh, const float* __restrict__ bh,
    char* __restrict__ wsb) {
  float* ws = (float*)wsb;
  int pt = blockIdx.x;
  int ot = blockIdx.y;
  int z = blockIdx.z;
  int tensor = z >> 2, b = z & 3;

  const float* X; const float* Wm; const float* bias;
  const float* meanA = nullptr; const float* rstdA = nullptr;
  if (tensor == 0)      { X = content; Wm = Wf; bias = bf; meanA = ws;        rstdA = ws + 1024; }
  else if (tensor == 1) { X = style;   Wm = Wg; bias = bg; meanA = ws + 2048; rstdA = ws + 3072; }
  else                  { X = style;   Wm = Wh; bias = bh; }

  __shared__ float Xs[32 * 132];
  __shared__ float Wt[32 * 68];

  int t = threadIdx.x;
  int p0 = pt * 128, o0 = ot * 64;
  int o_base = (t >> 4) * 4;
  int p_base = (t & 15) * 8;

  float bb[4];
  { float4 b4 = *(const float4*)&bias[o0 + o_base];
    bb[0] = b4.x; bb[1] = b4.y; bb[2] = b4.z; bb[3] = b4.w; }
  float acc[4][8];
#pragma unroll
  for (int oo = 0; oo < 4; ++oo)
#pragma unroll
    for (int pp = 0; pp < 8; ++pp) acc[oo][pp] = bb[oo];

  const float4* X4 = (const float4*)X;
  const float4* Wm4 = (const float4*)Wm;

  for (int kc = 0; kc < 8; ++kc) {
    int k0 = kc * 32;
    __syncthreads();
#pragma unroll
    for (int n = 0; n < 4; ++n) {
      int f = t + n * 256;
      int kk = f >> 5, p4 = f & 31;
      float4 v = X4[(size_t)(b * NC + k0 + kk) * (HW / 4) + (p0 / 4) + p4];
      if (tensor < 2) {
        float mC = meanA[b * NC + k0 + kk], rC = rstdA[b * NC + k0 + kk];
        v.x = (v.x - mC) * rC; v.y = (v.y - mC) * rC;
        v.z = (v.z - mC) * rC; v.w = (v.w - mC) * rC;
      }
      *(float4*)&Xs[kk * 132 + p4 * 4] = v;
    }
#pragma unroll
    for (int n = 0; n < 2; ++n) {
      int f = t + n * 256;
      int o = f >> 3, k4 = f & 7;
      float4 v = Wm4[(size_t)(o0 + o) * (NC / 4) + kc * 8 + k4];
      Wt[(k4 * 4 + 0) * 68 + o] = v.x;
      Wt[(k4 * 4 + 1) * 68 + o] = v.y;
      Wt[(k4 * 4 + 2) * 68 + o] = v.z;
      Wt[(k4 * 4 + 3) * 68 + o] = v.w;
    }
    __syncthreads();
#pragma unroll
    for (int kk = 0; kk < 32; ++kk) {
      float4 w4 = *(float4*)&Wt[kk * 68 + o_base];
      float4 xa = *(float4*)&Xs[kk * 132 + p_base];
      float4 xb = *(float4*)&Xs[kk * 132 + p_base + 4];
      float wv[4] = {w4.x, w4.y, w4.z, w4.w};
      float xv[8] = {xa.x, xa.y, xa.z, xa.w, xb.x, xb.y, xb.z, xb.w};
#pragma unroll
      for (int oo = 0; oo < 4; ++oo)
#pragma unroll
        for (int pp = 0; pp < 8; ++pp)
          acc[oo][pp] = fmaf(wv[oo], xv[pp], acc[oo][pp]);
    }
  }

  if (tensor < 2) {
    _Float16* dst = (_Float16*)(wsb + (tensor == 0 ? QF_OFF : KF_OFF));
#pragma unroll
    for (int pp = 0; pp < 8; ++pp) {
      half4v h;
      h[0] = (_Float16)acc[0][pp]; h[1] = (_Float16)acc[1][pp];
      h[2] = (_Float16)acc[2][pp]; h[3] = (_Float16)acc[3][pp];
      *(half4v*)&dst[((size_t)(b * HW) + p0 + p_base + pp) * 256 + o0 + o_base] = h;
    }
  } else {
    _Float16* dV  = (_Float16*)(wsb + VF_OFF);
    _Float16* dH  = (_Float16*)(wsb + V2H_OFF);
    _Float16* dL  = (_Float16*)(wsb + V2L_OFF);
#pragma unroll
    for (int oo = 0; oo < 4; ++oo) {
      int ch = o0 + o_base + oo;
      half8 hv, hh, hl;
#pragma unroll
      for (int pp = 0; pp < 8; ++pp) {
        _Float16 vh = (_Float16)acc[oo][pp];
        float vf = (float)vh;
        float v2 = vf * vf;
        _Float16 v2h = (_Float16)v2;
        _Float16 v2l = (_Float16)(v2 - (float)v2h);
        hv[pp] = vh; hh[pp] = v2h; hl[pp] = v2l;
      }
      size_t base = ((size_t)(b * NC) + ch) * HW + p0 + p_base;
      *(half8*)&dV[base] = hv;
      *(half8*)&dH[base] = hh;
      *(half8*)&dL[base] = hl;
    }
  }
}

// ---------------------------------------------------------------------------
// Kernel 3: flash attention, mfma_f32_16x16x32_f16.
// Block = 512 thr = 8 waves; q-tile 64. Wave = (qh 0..3, chh 0..1):
// 16 queries x 128 channels per wave -> accm/accs = 64 VGPRs, Aq = 32 VGPRs
// (no spills; round-3's 5.77 GB scratch WRITE_SIZE was the whole regression).
// Key tile = 32. Global->reg prefetch double-buffer for K/V/V2h/V2l streams.
// LDS 64KB: K[16K] | V[16K] | V2h[16K] | V2l[16K]; P (4 KB) aliases K.
// ---------------------------------------------------------------------------
__global__ __launch_bounds__(512, 2) void attn_kernel(
    const char* __restrict__ wsb, const float* __restrict__ content,
    float* __restrict__ dout) {
  const _Float16* Qf  = (const _Float16*)(wsb + QF_OFF);
  const _Float16* Kf  = (const _Float16*)(wsb + KF_OFF);
  const _Float16* Vf  = (const _Float16*)(wsb + VF_OFF);
  const _Float16* V2h = (const _Float16*)(wsb + V2H_OFF);
  const _Float16* V2l = (const _Float16*)(wsb + V2L_OFF);
  const float* meanC = (const float*)wsb;
  const float* rstdC = meanC + 1024;

  int qt = blockIdx.x, b = blockIdx.y;
  int t = threadIdx.x;
  int lane = t & 63;
  int w = t >> 6;     // 0..7
  int qh = w >> 1;    // 0..3: which 16 queries
  int chh = w & 1;    // 0..1: which 128 channels
  int q0 = qt * 64;
  int ml = lane & 15;
  int kg4 = lane >> 4;

  __shared__ int4 smem[4096];  // 64 KB
  _Float16* Kt   = (_Float16*)smem;                    // 16 KB
  _Float16* Vt   = (_Float16*)((char*)smem + 16384);
  _Float16* V2ht = (_Float16*)((char*)smem + 32768);
  _Float16* V2lt = (_Float16*)((char*)smem + 49152);
  _Float16* Pt   = (_Float16*)smem;                    // 4 KB, aliases Kt
  int4* kt16 = (int4*)Kt;
  int4* v16  = (int4*)Vt;
  int4* h16  = (int4*)V2ht;
  int4* l16  = (int4*)V2lt;

  // ---- Q A-frags: 16 queries x 256 ch per wave (32 VGPRs) ----
  half8 Aq[8];
#pragma unroll
  for (int ks = 0; ks < 8; ++ks) {
    size_t off = ((size_t)(b * HW) + q0 + qh * 16 + ml) * 256 + ks * 32 + kg4 * 8;
    Aq[ks] = *(const half8*)(Qf + off);
  }

  f32x4 accm[8], accs[8];
#pragma unroll
  for (int nt = 0; nt < 8; ++nt) {
    accm[nt] = (f32x4){0.f, 0.f, 0.f, 0.f};
    accs[nt] = (f32x4){0.f, 0.f, 0.f, 0.f};
  }
  float mrun[4], lrun[4];
#pragma unroll
  for (int r = 0; r < 4; ++r) { mrun[r] = -INFINITY; lrun[r] = 0.f; }

  // ---- staging geometry ----
  int k_key = t >> 4;   // 0..31
  int k_c0  = t & 15;   // granules c0, c0+16 (32 granules of 8ch per key)
  const int4* Kg = (const int4*)(Kf + (size_t)b * HW * 256);
  int v_kg  = t & 3;
  int v_chb = t >> 2;   // 0..127; ch = v_chb + 128*i
  const int4* Vg   = (const int4*)(Vf  + (size_t)b * NC * HW);
  const int4* V2g  = (const int4*)(V2h + (size_t)b * NC * HW);
  const int4* V2lg = (const int4*)(V2l + (size_t)b * NC * HW);

  int4 pk[2], pv[2], ph2[2], pl2[2];
  // prefetch tile 0
#pragma unroll
  for (int i = 0; i < 2; ++i) {
    int c = k_c0 + 16 * i;
    pk[i] = Kg[(size_t)k_key * 32 + c];
    int ch = v_chb + 128 * i;
    size_t gi = (size_t)ch * (HW / 8) + v_kg;
    pv[i] = Vg[gi]; ph2[i] = V2g[gi]; pl2[i] = V2lg[gi];
  }

  for (int kt = 0; kt < 128; ++kt) {
    __syncthreads();  // prev iter's LDS reads done

    // ---- write staged regs to LDS (swizzled) ----
#pragma unroll
    for (int i = 0; i < 2; ++i) {
      int c = k_c0 + 16 * i;
      kt16[c * 32 + (k_key ^ c)] = pk[i];
      int ch = v_chb + 128 * i;
      int di = v_kg * 256 + (ch ^ v_kg);
      v16[di] = pv[i]; h16[di] = ph2[i]; l16[di] = pl2[i];
    }
    // ---- prefetch next tile (wraps; overlaps this tile's compute) ----
    {
      int ktn = (kt + 1) & 127;
#pragma unroll
      for (int i = 0; i < 2; ++i) {
        int c = k_c0 + 16 * i;
        pk[i] = Kg[(size_t)(ktn * 32 + k_key) * 32 + c];
        int ch = v_chb + 128 * i;
        size_t gi = (size_t)ch * (HW / 8) + ktn * 4 + v_kg;
        pv[i] = Vg[gi]; ph2[i] = V2g[gi]; pl2[i] = V2lg[gi];
      }
    }
    __syncthreads();  // tiles visible

    // ---- QK^T ----
    f32x4 S[2];
    S[0] = (f32x4){0.f, 0.f, 0.f, 0.f};
    S[1] = (f32x4){0.f, 0.f, 0.f, 0.f};
#pragma unroll
    for (int ks = 0; ks < 8; ++ks) {
#pragma unroll
      for (int nt = 0; nt < 2; ++nt) {
        int key = nt * 16 + ml;
        int c = ks * 4 + kg4;
        half8 Bk = *(const half8*)(Kt + (c * 32 + (key ^ c)) * 8);
        S[nt] = __builtin_amdgcn_mfma_f32_16x16x32_f16(Aq[ks], Bk, S[nt], 0, 0, 0);
      }
    }

    // ---- online softmax ----
    bool noup = true;
    float alpha[4];
#pragma unroll
    for (int r = 0; r < 4; ++r) {
      float tm = fmaxf(S[0][r], S[1][r]);
      tm = fmaxf(tm, __shfl_xor(tm, 1, 64));
      tm = fmaxf(tm, __shfl_xor(tm, 2, 64));
      tm = fmaxf(tm, __shfl_xor(tm, 4, 64));
      tm = fmaxf(tm, __shfl_xor(tm, 8, 64));
      float mold = mrun[r];
      float mn = fmaxf(mold, tm);
      float a = __expf(mold - mn);
      alpha[r] = a;
      noup = noup && (mn == mold);
      mrun[r] = mn;
      float rs = 0.f;
#pragma unroll
      for (int nt = 0; nt < 2; ++nt) {
        float p = __expf(S[nt][r] - mn);
        _Float16 ph = (_Float16)p;
        S[nt][r] = (float)ph;  // keep rounded value
        rs += (float)ph;
      }
      rs += __shfl_xor(rs, 1, 64);
      rs += __shfl_xor(rs, 2, 64);
      rs += __shfl_xor(rs, 4, 64);
      rs += __shfl_xor(rs, 8, 64);
      lrun[r] = lrun[r] * a + rs;
    }
    if (!__all((int)noup)) {
#pragma unroll
      for (int nt = 0; nt < 8; ++nt)
#pragma unroll
        for (int r = 0; r < 4; ++r) {
          accm[nt][r] *= alpha[r];
          accs[nt][r] *= alpha[r];
        }
    }

    __syncthreads();  // all QK reads of Kt done before P overwrites it

    // ---- P -> LDS in A-layout: Pt[(keygran*64 + qloc)*8 + key&7] ----
    if (chh == 0) {
#pragma unroll
      for (int nt = 0; nt < 2; ++nt)
#pragma unroll
        for (int r = 0; r < 4; ++r) {
          int qloc = qh * 16 + kg4 * 4 + r;
          int key = nt * 16 + ml;
          Pt[((key >> 3) * 64 + qloc) * 8 + (key & 7)] = (_Float16)S[nt][r];
        }
    }
    __syncthreads();  // P visible

    // ---- PV ----
    half8 Ap = *(const half8*)(Pt + (kg4 * 64 + qh * 16 + ml) * 8);
#pragma unroll
    for (int nt = 0; nt < 8; ++nt) {
      int ch = chh * 128 + nt * 16 + ml;
      int gi = (kg4 * 256 + (ch ^ kg4)) * 8;
      half8 Bv = *(const half8*)(Vt + gi);
      half8 Bh = *(const half8*)(V2ht + gi);
      half8 Bl = *(const half8*)(V2lt + gi);
      accm[nt] = __builtin_amdgcn_mfma_f32_16x16x32_f16(Ap, Bv, accm[nt], 0, 0, 0);
      accs[nt] = __builtin_amdgcn_mfma_f32_16x16x32_f16(Ap, Bh, accs[nt], 0, 0, 0);
      accs[nt] = __builtin_amdgcn_mfma_f32_16x16x32_f16(Ap, Bl, accs[nt], 0, 0, 0);
    }
  }

  // ---- finalize ----
  float inv[4];
#pragma unroll
  for (int r = 0; r < 4; ++r) inv[r] = 1.0f / lrun[r];
#pragma unroll
  for (int nt = 0; nt < 8; ++nt)
#pragma unroll
    for (int r = 0; r < 4; ++r) {
      float mu = accm[nt][r] * inv[r];
      float s2 = accs[nt][r] * inv[r];
      float var = s2 - mu * mu;
      accm[nt][r] = mu;
      accs[nt][r] = sqrtf(fmaxf(var, 0.f));
    }

  // ---- coalesced epilogue via LDS transpose: 4 phases of 64 channels ----
  float* MUL = (float*)smem;            // [64][68]
  float* SDL = MUL + 64 * 68;
#pragma unroll 1
  for (int ph = 0; ph < 4; ++ph) {
    __syncthreads();
    if (chh == (ph >> 1)) {
      int ntb = (ph & 1) * 4;
#pragma unroll
      for (int nn = 0; nn < 4; ++nn)
#pragma unroll
        for (int r = 0; r < 4; ++r) {
          int row64 = nn * 16 + ml;
          int ql = qh * 16 + kg4 * 4 + r;
          MUL[row64 * 68 + ql] = accm[ntb + nn][r];
          SDL[row64 * 68 + ql] = accs[ntb + nn][r];
        }
    }
    __syncthreads();
    int qq = (t & 15) * 4;
#pragma unroll
    for (int i = 0; i < 2; ++i) {
      int chl = (t >> 4) + 32 * i;
      int ch = ph * 64 + chl;
      float4 mu4 = *(float4*)&MUL[chl * 68 + qq];
      float4 sd4 = *(float4*)&SDL[chl * 68 + qq];
      size_t base = ((size_t)(b * NC) + ch) * HW + q0 + qq;
      float4 c4 = *(const float4*)&content[base];
      float mC = meanC[b * NC + ch];
      float rC = rstdC[b * NC + ch];
      float4 o4;
      o4.x = sd4.x * ((c4.x - mC) * rC) + mu4.x;
      o4.y = sd4.y * ((c4.y - mC) * rC) + mu4.y;
      o4.z = sd4.z * ((c4.z - mC) * rC) + mu4.z;
      o4.w = sd4.w * ((c4.w - mC) * rC) + mu4.w;
      *(float4*)&dout[base] = o4;
      *(float4*)&dout[TEN + base] = mu4;
      *(float4*)&dout[2 * TEN + base] = sd4;
    }
  }
}

// ---------------------------------------------------------------------------
extern "C" void kernel_launch(void* const* d_in, const int* in_sizes, int n_in,
                              void* d_out, int out_size, void* d_ws, size_t ws_size,
                              hipStream_t stream) {
  const float* content = (const float*)d_in[0];
  const float* style   = (const float*)d_in[1];
  const float* Wf = (const float*)d_in[2];
  const float* bf = (const float*)d_in[3];
  const float* Wg = (const float*)d_in[4];
  const float* bg = (const float*)d_in[5];
  const float* Wh = (const float*)d_in[6];
  const float* bh = (const float*)d_in[7];
  char* wsb = (char*)d_ws;
  float* out = (float*)d_out;

  hipLaunchKernelGGL(stats_kernel, dim3(2048), dim3(256), 0, stream,
                     content, style, (float*)wsb);
  hipLaunchKernelGGL(proj_kernel, dim3(32, 4, 12), dim3(256), 0, stream,
                     content, style, Wf, bf, Wg, bg, Wh, bh, wsb);
  hipLaunchKernelGGL(attn_kernel, dim3(64, 4), dim3(512), 0, stream,
                     wsb, content, out);
}